// Round 16
// baseline (824.391 us; speedup 1.0000x reference)
//
#include <hip/hip_runtime.h>

// WSDModel: X=E_v[M_s]; S=(X W_A) X^T + causal-dist bias; A=softmax(S);
// H=LN(A X W_O + X); y=H E_y^T.  B=4 N=4096 D=512 V=50257 Y=16000.
// Outputs (f32, concat): y_logits [4,4096,16000], A [4,4096,4096].
// Softmax: fixed shift m=0 (safe: |S|<=~3 above bias). k3 emits E=exp(S) bf16
// AND zero-fills A's strictly-upper mirror tiles (hidden under its MFMA).
// inv-normalization commutes through W_O (applied in k6b). Qc_raw = E@(X W_O)
// via k_wot's pre-transposed (X W_O)^T. k4 (now 206MB) runs AFTER k5 so Ebf
// stays L3-hot. k7 epilogue: lanes span consecutive y-columns (coalescing is
// across lanes, not per-lane width).

#define DEVINL __device__ __forceinline__

typedef __attribute__((ext_vector_type(8))) short bf16x8;
typedef __attribute__((ext_vector_type(4))) float f32x4;
typedef unsigned short u16;

#define BB 4
#define NN 4096
#define DD 512
#define YY 16000
#define YPAD 16128  // 63 tiles of 256
#define ROWS (BB * NN)  // 16384

DEVINL u16 f2bf(float x) {  // RNE f32 -> bf16 bits
  unsigned u = __float_as_uint(x);
  return (u16)((u + 0x7fffu + ((u >> 16) & 1u)) >> 16);
}

DEVINL float bf2f(u16 h) { return __uint_as_float((unsigned)h << 16); }

DEVINL void gload16(const void* g, void* l) {  // async global->LDS, 16B/lane
  __builtin_amdgcn_global_load_lds(
      (const __attribute__((address_space(1))) void*)g,
      (__attribute__((address_space(3))) void*)l, 16, 0, 0);
}

DEVINL void zero_acc(f32x4 acc[4][4]) {
#pragma unroll
  for (int m = 0; m < 4; ++m)
#pragma unroll
    for (int n = 0; n < 4; ++n) {
      acc[m][n][0] = 0.f; acc[m][n][1] = 0.f;
      acc[m][n][2] = 0.f; acc[m][n][3] = 0.f;
    }
}

// ---- core: C[128x128] += A[128xK] * B[128xK]^T, bf16 operands, m97 structure
DEVINL void gemm_bt_core(const u16* __restrict__ A, int lda,
                         const u16* __restrict__ Bm, int ldb, int ksteps,
                         u16* sA, u16* sB, f32x4 acc[4][4], int tid) {
  const int lane = tid & 63, w = tid >> 6;
  const int wr = (w >> 1) * 64, wc = (w & 1) * 64;
  const int c0 = w * 128 + lane, c1 = c0 + 64;  // 16B chunk ids (512 total)
  const u16* gA0 = A + (size_t)(c0 >> 2) * lda + (c0 & 3) * 8;
  const u16* gA1 = A + (size_t)(c1 >> 2) * lda + (c1 & 3) * 8;
  const u16* gB0 = Bm + (size_t)(c0 >> 2) * ldb + (c0 & 3) * 8;
  const u16* gB1 = Bm + (size_t)(c1 >> 2) * ldb + (c1 & 3) * 8;
  u16* lA0 = sA + w * 1024;  u16* lA1 = lA0 + 512;  // wave-uniform LDS bases
  u16* lB0 = sB + w * 1024;  u16* lB1 = lB0 + 512;
  const int fr = lane & 15, fk = (lane >> 4) * 8;

  for (int kt = 0; kt < ksteps; ++kt) {
    __syncthreads();
    gload16(gA0 + kt * 32, lA0);
    gload16(gA1 + kt * 32, lA1);
    gload16(gB0 + kt * 32, lB0);
    gload16(gB1 + kt * 32, lB1);
    __syncthreads();
    bf16x8 af[4], bfv[4];
#pragma unroll
    for (int m = 0; m < 4; ++m)
      af[m] = *(const bf16x8*)(sA + (wr + m * 16 + fr) * 32 + fk);
#pragma unroll
    for (int n = 0; n < 4; ++n)
      bfv[n] = *(const bf16x8*)(sB + (wc + n * 16 + fr) * 32 + fk);
#pragma unroll
    for (int m = 0; m < 4; ++m)
#pragma unroll
      for (int n = 0; n < 4; ++n)
        acc[m][n] = __builtin_amdgcn_mfma_f32_16x16x32_bf16(af[m], bfv[n],
                                                            acc[m][n], 0, 0, 0);
  }
}

// ---- 256x256 deep-pipeline core (BK=64, 8 waves, K=512 fixed) ------------
#define C256_STAGE(kt, buf)                                    \
  {                                                            \
    const u16* a0 = Ag + (kt) * 64;                            \
    const u16* b0 = Bg + (kt) * 64;                            \
    u16* Lb = lds + (buf) * 32768;                             \
    gload16(a0 + offE0, Lb + d0);                              \
    gload16(a0 + offE1, Lb + d1);                              \
    gload16(a0 + 65536 + offE0, Lb + 8192 + d0);               \
    gload16(a0 + 65536 + offE1, Lb + 8192 + d1);               \
    gload16(b0 + offE0, Lb + 16384 + d0);                      \
    gload16(b0 + offE1, Lb + 16384 + d1);                      \
    gload16(b0 + 65536 + offE0, Lb + 24576 + d0);              \
    gload16(b0 + 65536 + offE1, Lb + 24576 + d1);              \
  }

DEVINL void core256(const u16* __restrict__ Ag, const u16* __restrict__ Bg,
                    u16* lds, f32x4 (&acc)[8][4], int tid) {
  const int lane = tid & 63, w = tid >> 6;
  const int wm = w >> 2, wn = w & 3;

  int offE0, offE1;
  {
    int q = tid;
    int r = (((q >> 6) >> 1) << 4) | ((q >> 2) & 15);
    int c = (((q >> 6) & 1) << 5) |
            (((q & 3) << 3) ^ (((q >> 5) & 1) << 4) ^ (((q >> 4) & 1) << 3));
    offE0 = r * DD + c;
    q = 512 + tid;
    r = (((q >> 6) >> 1) << 4) | ((q >> 2) & 15);
    c = (((q >> 6) & 1) << 5) |
        (((q & 3) << 3) ^ (((q >> 5) & 1) << 4) ^ (((q >> 4) & 1) << 3));
    offE1 = r * DD + c;
  }
  const int d0 = w * 512, d1 = 4096 + w * 512;  // u16 units in a half region

  int x = (lane & 15) * 64 + ((lane >> 4) & 3) * 16;  // bytes
  int fxu = (x ^ (((x >> 9) & 1) << 5) ^ (((x >> 8) & 1) << 4)) >> 1;

#pragma unroll
  for (int m = 0; m < 8; ++m)
#pragma unroll
    for (int n = 0; n < 4; ++n) {
      acc[m][n][0] = 0.f; acc[m][n][1] = 0.f;
      acc[m][n][2] = 0.f; acc[m][n][3] = 0.f;
    }

  C256_STAGE(0, 0);
  C256_STAGE(1, 1);
  asm volatile("s_waitcnt vmcnt(8)" ::: "memory");  // K-tile 0 landed
  __syncthreads();

  for (int c = 0; c < 8; ++c) {
    const u16* L = lds + (c & 1) * 32768;
    const u16* pa = L + wm * 8192;
    const u16* pb = L + 16384 + (wn >> 1) * 8192 + (wn & 1) * 4096;
    bf16x8 af[4][2], bf[4][2];
    // phase 1: quadrant (m0-3, n0-1)
#pragma unroll
    for (int n = 0; n < 2; ++n)
#pragma unroll
      for (int ks = 0; ks < 2; ++ks)
        bf[n][ks] = *(const bf16x8*)(pb + (n * 2 + ks) * 512 + fxu);
#pragma unroll
    for (int m = 0; m < 4; ++m)
#pragma unroll
      for (int ks = 0; ks < 2; ++ks)
        af[m][ks] = *(const bf16x8*)(pa + (m * 2 + ks) * 512 + fxu);
    __builtin_amdgcn_s_setprio(1);
#pragma unroll
    for (int m = 0; m < 4; ++m)
#pragma unroll
      for (int n = 0; n < 2; ++n)
#pragma unroll
        for (int ks = 0; ks < 2; ++ks)
          acc[m][n] = __builtin_amdgcn_mfma_f32_16x16x32_bf16(
              af[m][ks], bf[n][ks], acc[m][n], 0, 0, 0);
    __builtin_amdgcn_s_setprio(0);
    // phase 2: (m0-3, n2-3)
#pragma unroll
    for (int n = 2; n < 4; ++n)
#pragma unroll
      for (int ks = 0; ks < 2; ++ks)
        bf[n][ks] = *(const bf16x8*)(pb + (n * 2 + ks) * 512 + fxu);
    __builtin_amdgcn_s_setprio(1);
#pragma unroll
    for (int m = 0; m < 4; ++m)
#pragma unroll
      for (int n = 2; n < 4; ++n)
#pragma unroll
        for (int ks = 0; ks < 2; ++ks)
          acc[m][n] = __builtin_amdgcn_mfma_f32_16x16x32_bf16(
              af[m][ks], bf[n][ks], acc[m][n], 0, 0, 0);
    __builtin_amdgcn_s_setprio(0);
    // phase 3: (m4-7, n0-1)
#pragma unroll
    for (int m = 0; m < 4; ++m)
#pragma unroll
      for (int ks = 0; ks < 2; ++ks)
        af[m][ks] = *(const bf16x8*)(pa + ((m + 4) * 2 + ks) * 512 + fxu);
    __builtin_amdgcn_s_setprio(1);
#pragma unroll
    for (int m = 0; m < 4; ++m)
#pragma unroll
      for (int n = 0; n < 2; ++n)
#pragma unroll
        for (int ks = 0; ks < 2; ++ks)
          acc[m + 4][n] = __builtin_amdgcn_mfma_f32_16x16x32_bf16(
              af[m][ks], bf[n][ks], acc[m + 4][n], 0, 0, 0);
    // phase 4: (m4-7, n2-3)
#pragma unroll
    for (int m = 0; m < 4; ++m)
#pragma unroll
      for (int n = 2; n < 4; ++n)
#pragma unroll
        for (int ks = 0; ks < 2; ++ks)
          acc[m + 4][n] = __builtin_amdgcn_mfma_f32_16x16x32_bf16(
              af[m][ks], bf[n][ks], acc[m + 4][n], 0, 0, 0);
    __builtin_amdgcn_s_setprio(0);

    __syncthreads();  // all waves done READING buffer (c&1)
    if (c < 6) {
      C256_STAGE(c + 2, c & 1);  // overwrite just-read buffer (post-barrier)
      asm volatile("s_waitcnt vmcnt(8)" ::: "memory");  // K-tile c+1 landed
    } else if (c == 6) {
      asm volatile("s_waitcnt vmcnt(0)" ::: "memory");  // K-tile 7 landed
    }
    __syncthreads();
  }
}

// ---- merged prep: gather + 2x W transpose + Ey cast (one launch) ---------
__global__ __launch_bounds__(256) void prep_all(const int* __restrict__ Ms,
                                                const float* __restrict__ Ev,
                                                const float* __restrict__ WA,
                                                const float* __restrict__ WO,
                                                const float* __restrict__ Ey,
                                                u16* __restrict__ Xb,
                                                u16* __restrict__ WAt,
                                                u16* __restrict__ WOt,
                                                u16* __restrict__ Eyb) {
  __shared__ u16 t[64][65];
  int bx = blockIdx.x, tid = threadIdx.x;
  if (bx < 8192) {  // gather: 2 rows per block
    int row = bx * 2 + (tid >> 7);
    int t4 = tid & 127;
    int tok = Ms[row];
    float4 v = *(const float4*)(Ev + (size_t)tok * DD + t4 * 4);
    *(ushort4*)(Xb + (size_t)row * DD + t4 * 4) =
        make_ushort4(f2bf(v.x), f2bf(v.y), f2bf(v.z), f2bf(v.w));
  } else if (bx < 8320) {  // W transpose, 64 blocks each
    int k = bx - 8192;
    const float* W = (k < 64) ? WA : WO;
    u16* Wt = (k < 64) ? WAt : WOt;
    k &= 63;
    int dt = k >> 3, et = k & 7;
#pragma unroll
    for (int p = 0; p < 16; ++p) {
      int e = tid + 256 * p; int r = e >> 6, c = e & 63;
      t[r][c] = f2bf(W[(size_t)(dt * 64 + r) * DD + et * 64 + c]);
    }
    __syncthreads();
#pragma unroll
    for (int p = 0; p < 16; ++p) {
      int e = tid + 256 * p; int r = e >> 6, c = e & 63;
      Wt[(size_t)(et * 64 + r) * DD + dt * 64 + c] = t[c][r];
    }
  } else {  // prep_ey: 8064 blocks
    size_t i4 = (size_t)(bx - 8320) * 256 + tid;
    size_t row = i4 >> 7;
    ushort4 h;
    if (row < YY) {
      float4 v = *(const float4*)(Ey + i4 * 4);
      h = make_ushort4(f2bf(v.x), f2bf(v.y), f2bf(v.z), f2bf(v.w));
    } else {
      h = make_ushort4(0, 0, 0, 0);
    }
    *(ushort4*)(Eyb + i4 * 4) = h;
  }
}

// ---- k2w: merged k2 (XW_A) + k_wot ((X W_O)^T) — both read Xb ------------
__global__ __launch_bounds__(256) void k2w(const u16* __restrict__ Xb,
                                           const u16* __restrict__ WAt,
                                           const u16* __restrict__ WOt,
                                           u16* __restrict__ XWb,
                                           u16* __restrict__ XWoT) {
  __shared__ u16 sA[4096], sB[4096];
  f32x4 acc[4][4]; zero_acc(acc);
  int tid = threadIdx.x, bx = blockIdx.x;
  int lane = tid & 63, w = tid >> 6;
  int wr = (w >> 1) * 64, wc = (w & 1) * 64;
  int cr = (lane >> 4) * 4, cc = lane & 15;
  if (bx < 512) {  // k2: XWb[i][e] = X[i]. WAt[e]
    size_t row0 = (size_t)(bx >> 2) * 128, col0 = (size_t)(bx & 3) * 128;
    gemm_bt_core(Xb + row0 * DD, DD, WAt + col0 * DD, DD, DD / 32, sA, sB,
                 acc, tid);
#pragma unroll
    for (int m = 0; m < 4; ++m)
#pragma unroll
      for (int n = 0; n < 4; ++n)
#pragma unroll
        for (int r = 0; r < 4; ++r) {
          size_t gi = row0 + wr + m * 16 + cr + r;
          size_t gj = col0 + wc + n * 16 + cc;
          XWb[gi * DD + gj] = f2bf(acc[m][n][r]);
        }
  } else {  // k_wot: XWoT[b][e][i] = WOt[e] . X[b*NN+i]
    int j = bx - 512;
    int et = j & 3, it = (j >> 2) & 31, b = j >> 7;
    const u16* Ap = WOt + (size_t)et * 128 * DD;
    const u16* Bp = Xb + ((size_t)b * NN + it * 128) * DD;
    gemm_bt_core(Ap, DD, Bp, DD, DD / 32, sA, sB, acc, tid);
#pragma unroll
    for (int m = 0; m < 4; ++m)
#pragma unroll
      for (int n = 0; n < 4; ++n)
#pragma unroll
        for (int r = 0; r < 4; ++r) {
          size_t e = (size_t)et * 128 + wr + m * 16 + cr + r;
          size_t i = (size_t)it * 128 + wc + n * 16 + cc;
          XWoT[((size_t)b * DD + e) * NN + i] = f2bf(acc[m][n][r]);
        }
  }
}

// k3: triangular m97 grid; epilogue computes E=exp(S) (fixed shift m=0),
// writes bf16 E; strictly-lower blocks also zero-fill the mirrored upper
// f32 A tile (hidden under k3's MFMA time — k3 is compute-bound).
__global__ __launch_bounds__(256) void k3_scores(const u16* __restrict__ XWb,
                                                 const u16* __restrict__ Xb,
                                                 u16* __restrict__ Ebf,
                                                 float* __restrict__ Aout) {
  int t = blockIdx.x, b = blockIdx.z;
  int ib = (int)((sqrtf(8.f * (float)t + 1.f) - 1.f) * 0.5f);
  while ((ib + 1) * (ib + 2) / 2 <= t) ++ib;
  while (ib * (ib + 1) / 2 > t) --ib;
  int jb = t - ib * (ib + 1) / 2;
  __shared__ u16 sA[4096], sB[4096];
  f32x4 acc[4][4]; zero_acc(acc);
  int tid = threadIdx.x;
  const u16* Ap = XWb + ((size_t)b * NN + ib * 128) * DD;
  const u16* Bp = Xb  + ((size_t)b * NN + jb * 128) * DD;
  gemm_bt_core(Ap, DD, Bp, DD, DD / 32, sA, sB, acc, tid);
  int lane = tid & 63, w = tid >> 6;
  int wr = (w >> 1) * 64, wc = (w & 1) * 64;
  int cr = (lane >> 4) * 4, cc = lane & 15;
  u16* Eb = Ebf + (size_t)b * NN * NN;
#pragma unroll
  for (int m = 0; m < 4; ++m)
#pragma unroll
    for (int n = 0; n < 4; ++n)
#pragma unroll
      for (int r = 0; r < 4; ++r) {
        int i = ib * 128 + wr + m * 16 + cr + r;
        int j = jb * 128 + wc + n * 16 + cc;
        float e = (j > i) ? 0.f : __expf(acc[m][n][r] - (float)(i - j));
        Eb[(size_t)i * NN + j] = f2bf(e);
      }
  if (jb < ib) {  // zero f32 A tile (rows jb*128.., cols ib*128..): all j>i
    float* Az = Aout + (size_t)b * NN * NN + ((size_t)jb * 128) * NN + ib * 128;
    f32x4 z = {0.f, 0.f, 0.f, 0.f};
#pragma unroll
    for (int p = 0; p < 16; ++p) {
      int e = tid + p * 256;
      int r = e >> 5, c4 = e & 31;  // 128 rows x 32 16B-chunks
      *(f32x4*)(Az + (size_t)r * NN + c4 * 4) = z;
    }
  }
}

// k5: rawQc = E @ (X W_O)  (no normalization — inv applied in k6b)
__global__ __launch_bounds__(256) void k5_ax(const u16* __restrict__ Ebf,
                                             const u16* __restrict__ XWoT,
                                             u16* __restrict__ Qcb) {
  int u = blockIdx.x;
  int half = u >> 8, v = u & 255;
  int ib = v & 31; if (half) ib = 31 - ib;
  int db = (v >> 5) & 3;
  int b = (half << 1) | (v >> 7);
  __shared__ u16 sA[4096], sB[4096];
  f32x4 acc[4][4]; zero_acc(acc);
  int tid = threadIdx.x;
  const u16* Ap = Ebf + ((size_t)b * NN + ib * 128) * NN;
  const u16* Bp = XWoT + ((size_t)b * DD + db * 128) * NN;
  gemm_bt_core(Ap, NN, Bp, NN, (ib + 1) * 4, sA, sB, acc, tid);
  int lane = tid & 63, w = tid >> 6;
  int wr = (w >> 1) * 64, wc = (w & 1) * 64;
  int cr = (lane >> 4) * 4, cc = lane & 15;
#pragma unroll
  for (int m = 0; m < 4; ++m)
#pragma unroll
    for (int n = 0; n < 4; ++n)
#pragma unroll
      for (int r = 0; r < 4; ++r) {
        int i = ib * 128 + wr + m * 16 + cr + r;
        int d = db * 128 + wc + n * 16 + cc;
        Qcb[((size_t)b * NN + i) * DD + d] = f2bf(acc[m][n][r]);
      }
}

// k4: row sums of E -> invb; write normalized f32 A for j < padend only
// (upper zeros were written by k3's mirror fill). Runs AFTER k5 so its
// write doesn't evict Ebf from L3 before k5.
__global__ __launch_bounds__(256) void k4_softmax(const u16* __restrict__ Ebf,
                                                  float* __restrict__ Aout,
                                                  float* __restrict__ invb) {
  __shared__ u16 srow[NN];  // 8KB
  __shared__ float red[4];
  size_t row = blockIdx.x;
  int i = (int)(row & (NN - 1));
  const u16* E = Ebf + row * (size_t)NN;
  float* S = Aout + row * (size_t)NN;
  int len = i + 1, tid = threadIdx.x;
  int padend = (len + 127) & ~127;  // k3 wrote exactly j < padend
  int nc = padend >> 3;             // 16B chunks
  for (int v = tid; v < nc; v += 256)
    *(uint4*)(srow + v * 8) = *(const uint4*)(E + v * 8);
  __syncthreads();
  float l = 0.f;
  for (int v = tid; v < nc; v += 256) {
    uint4 x = *(const uint4*)(srow + v * 8);
    l += bf2f((u16)(x.x & 0xffff)) + bf2f((u16)(x.x >> 16));
    l += bf2f((u16)(x.y & 0xffff)) + bf2f((u16)(x.y >> 16));
    l += bf2f((u16)(x.z & 0xffff)) + bf2f((u16)(x.z >> 16));
    l += bf2f((u16)(x.w & 0xffff)) + bf2f((u16)(x.w >> 16));
  }
#pragma unroll
  for (int o = 32; o; o >>= 1) l += __shfl_xor(l, o);
  if ((tid & 63) == 0) red[tid >> 6] = l;
  __syncthreads();
  float inv = 1.f / (red[0] + red[1] + red[2] + red[3]);
  if (tid == 0) invb[row] = inv;
  for (int v = tid; v < (padend >> 2); v += 256) {
    int k = v * 4;
    ushort4 e = *(const ushort4*)(srow + k);
    float4 a = make_float4(bf2f(e.x) * inv, bf2f(e.y) * inv,
                           bf2f(e.z) * inv, bf2f(e.w) * inv);
    *(float4*)(S + k) = a;
  }
}

// k6b: H = LN(inv[i]*rawQc + X)
__global__ __launch_bounds__(128) void k6b_ln(const u16* __restrict__ Qcb,
                                              const u16* __restrict__ Xb,
                                              const float* __restrict__ invb,
                                              const float* __restrict__ gamma,
                                              const float* __restrict__ beta,
                                              u16* __restrict__ Hb) {
  int row = blockIdx.x, tid = threadIdx.x;
  float inv = invb[row];
  ushort4 qu = *(const ushort4*)(Qcb + (size_t)row * DD + tid * 4);
  ushort4 xu = *(const ushort4*)(Xb + (size_t)row * DD + tid * 4);
  float v0 = bf2f(qu.x) * inv + bf2f(xu.x), v1 = bf2f(qu.y) * inv + bf2f(xu.y);
  float v2 = bf2f(qu.z) * inv + bf2f(xu.z), v3 = bf2f(qu.w) * inv + bf2f(xu.w);
  float s = v0 + v1 + v2 + v3;
  float s2 = v0 * v0 + v1 * v1 + v2 * v2 + v3 * v3;
#pragma unroll
  for (int o = 32; o; o >>= 1) { s += __shfl_xor(s, o); s2 += __shfl_xor(s2, o); }
  __shared__ float r1[2], r2[2];
  int lane = tid & 63, w = tid >> 6;
  if (lane == 0) { r1[w] = s; r2[w] = s2; }
  __syncthreads();
  s = r1[0] + r1[1]; s2 = r2[0] + r2[1];
  float mu = s * (1.f / 512.f);
  float var = s2 * (1.f / 512.f) - mu * mu;
  float rs = 1.f / sqrtf(var + 1e-5f);
  float4 g  = *(const float4*)(gamma + tid * 4);
  float4 be = *(const float4*)(beta + tid * 4);
  ushort4 h = make_ushort4(f2bf((v0 - mu) * rs * g.x + be.x),
                           f2bf((v1 - mu) * rs * g.y + be.y),
                           f2bf((v2 - mu) * rs * g.z + be.z),
                           f2bf((v3 - mu) * rs * g.w + be.w));
  *(ushort4*)(Hb + (size_t)row * DD + tid * 4) = h;
}

// ---- k7: y = H E_y^T on the 256^2 core, direct stores (lanes 0-15 span
// consecutive y-columns -> 64B/quarter-wave coalescing) --------------------
__global__ __launch_bounds__(512, 2) void k7_logits(const u16* __restrict__ Hb,
                                                    const u16* __restrict__ Eyb,
                                                    float* __restrict__ Yout) {
  __shared__ u16 lds[65536];  // 128 KB
  const int tid = threadIdx.x;
  const int lane = tid & 63, w = tid >> 6;
  const int wm = w >> 2, wn = w & 3;

  // bijective XCD swizzle (4032 % 8 == 0); consecutive swz share B panel
  int id = blockIdx.x;
  int swz = (id & 7) * (4032 / 8) + (id >> 3);
  size_t row0 = (size_t)(swz & 63) * 256;
  size_t col0 = (size_t)(swz >> 6) * 256;

  f32x4 acc[8][4];
  core256(Hb + row0 * DD, Eyb + col0 * DD, lds, acc, tid);

  // epilogue: direct plain stores
  const int cr = (lane >> 4) * 4, cc = lane & 15;
#pragma unroll
  for (int m = 0; m < 8; ++m)
#pragma unroll
    for (int n = 0; n < 4; ++n) {
      size_t gj = col0 + wn * 64 + n * 16 + cc;
      if (gj < YY) {
        size_t gi = row0 + wm * 128 + m * 16 + cr;
#pragma unroll
        for (int rr = 0; rr < 4; ++rr)
          Yout[(gi + rr) * (size_t)YY + gj] = acc[m][n][rr];
      }
    }
}

extern "C" void kernel_launch(void* const* d_in, const int* in_sizes, int n_in,
                              void* d_out, int out_size, void* d_ws, size_t ws_size,
                              hipStream_t stream) {
  (void)in_sizes; (void)n_in; (void)out_size; (void)ws_size;
  const int*   Ms    = (const int*)d_in[0];
  const float* Ev    = (const float*)d_in[1];
  const float* Ey    = (const float*)d_in[2];
  const float* WA    = (const float*)d_in[3];
  const float* WO    = (const float*)d_in[4];
  const float* gamma = (const float*)d_in[5];
  const float* beta  = (const float*)d_in[6];

  float* Yout = (float*)d_out;
  float* Aout = Yout + (size_t)BB * NN * YY;  // A region of d_out

  // workspace carve (~236 MB)
  char* w = (char*)d_ws;
  u16* Xb   = (u16*)w; w += (size_t)ROWS * DD * 2;     // 16.8 MB
  u16* XWoT = (u16*)w; w += (size_t)BB * DD * NN * 2;  // 16.8 MB ((X W_O)^T)
  u16* XWb  = (u16*)w; w += (size_t)ROWS * DD * 2;     // 16.8 MB
  u16* Hb   = (u16*)w; w += (size_t)ROWS * DD * 2;     // 16.8 MB
  u16* WAt  = (u16*)w; w += (size_t)DD * DD * 2;       // 0.5 MB
  u16* WOt  = (u16*)w; w += (size_t)DD * DD * 2;       // 0.5 MB
  u16* Eyb  = (u16*)w; w += (size_t)YPAD * DD * 2;     // 16.5 MB (padded)
  u16* Ebf  = (u16*)w; w += (size_t)ROWS * NN * 2;     // 134.2 MB (exp(S) bf16)
  float* invb = (float*)w; w += (size_t)ROWS * 4;      // 64 KB (row inv sums)
  u16* Qcb = XWb;  // aliases XWb — dead after k3; k5 writes it post-k3

  prep_all<<<16384, 256, 0, stream>>>(Ms, Ev, WA, WO, Ey, Xb, WAt, WOt, Eyb);
  k2w<<<1024, 256, 0, stream>>>(Xb, WAt, WOt, XWb, XWoT);
  k3_scores<<<dim3(528, 1, BB), 256, 0, stream>>>(XWb, Xb, Ebf, Aout);
  k5_ax<<<512, 256, 0, stream>>>(Ebf, XWoT, Qcb);
  k4_softmax<<<ROWS, 256, 0, stream>>>(Ebf, Aout, invb);
  k6b_ln<<<ROWS, 128, 0, stream>>>(Qcb, Xb, invb, gamma, beta, Hb);
  k7_logits<<<dim3(64 * 63), 512, 0, stream>>>(Hb, Eyb, Yout);
}

// Round 17
// 807.465 us; speedup vs baseline: 1.0210x; 1.0210x over previous
//
#include <hip/hip_runtime.h>

// WSDModel: X=E_v[M_s]; S=(X W_A) X^T + causal-dist bias; A=softmax(S);
// H=LN(A X W_O + X); y=H E_y^T.  B=4 N=4096 D=512 V=50257 Y=16000.
// Outputs (f32, concat): y_logits [4,4096,16000], A [4,4096,4096].
// Softmax: fixed shift m=0 (safe: |S|<=~3 above bias). k3 emits E=exp(S) bf16
// ONLY (no A zero-fill — R16 lesson: extra 134MB write stream in k3 evicts
// Ebf from L3 before k5). inv-normalization commutes through W_O (k6b).
// Qc_raw = E@(X W_O) via pre-transposed (X W_O)^T (k2w). k4 (268MB A-write,
// incl. upper zeros) runs AFTER k5 so Ebf stays L3-hot. k7 epilogue: lanes
// span consecutive y-columns (coalescing is across lanes, not per-lane width).

#define DEVINL __device__ __forceinline__

typedef __attribute__((ext_vector_type(8))) short bf16x8;
typedef __attribute__((ext_vector_type(4))) float f32x4;
typedef unsigned short u16;

#define BB 4
#define NN 4096
#define DD 512
#define YY 16000
#define YPAD 16128  // 63 tiles of 256
#define ROWS (BB * NN)  // 16384

DEVINL u16 f2bf(float x) {  // RNE f32 -> bf16 bits
  unsigned u = __float_as_uint(x);
  return (u16)((u + 0x7fffu + ((u >> 16) & 1u)) >> 16);
}

DEVINL float bf2f(u16 h) { return __uint_as_float((unsigned)h << 16); }

DEVINL void gload16(const void* g, void* l) {  // async global->LDS, 16B/lane
  __builtin_amdgcn_global_load_lds(
      (const __attribute__((address_space(1))) void*)g,
      (__attribute__((address_space(3))) void*)l, 16, 0, 0);
}

DEVINL void zero_acc(f32x4 acc[4][4]) {
#pragma unroll
  for (int m = 0; m < 4; ++m)
#pragma unroll
    for (int n = 0; n < 4; ++n) {
      acc[m][n][0] = 0.f; acc[m][n][1] = 0.f;
      acc[m][n][2] = 0.f; acc[m][n][3] = 0.f;
    }
}

// ---- core: C[128x128] += A[128xK] * B[128xK]^T, bf16 operands, m97 structure
DEVINL void gemm_bt_core(const u16* __restrict__ A, int lda,
                         const u16* __restrict__ Bm, int ldb, int ksteps,
                         u16* sA, u16* sB, f32x4 acc[4][4], int tid) {
  const int lane = tid & 63, w = tid >> 6;
  const int wr = (w >> 1) * 64, wc = (w & 1) * 64;
  const int c0 = w * 128 + lane, c1 = c0 + 64;  // 16B chunk ids (512 total)
  const u16* gA0 = A + (size_t)(c0 >> 2) * lda + (c0 & 3) * 8;
  const u16* gA1 = A + (size_t)(c1 >> 2) * lda + (c1 & 3) * 8;
  const u16* gB0 = Bm + (size_t)(c0 >> 2) * ldb + (c0 & 3) * 8;
  const u16* gB1 = Bm + (size_t)(c1 >> 2) * ldb + (c1 & 3) * 8;
  u16* lA0 = sA + w * 1024;  u16* lA1 = lA0 + 512;  // wave-uniform LDS bases
  u16* lB0 = sB + w * 1024;  u16* lB1 = lB0 + 512;
  const int fr = lane & 15, fk = (lane >> 4) * 8;

  for (int kt = 0; kt < ksteps; ++kt) {
    __syncthreads();
    gload16(gA0 + kt * 32, lA0);
    gload16(gA1 + kt * 32, lA1);
    gload16(gB0 + kt * 32, lB0);
    gload16(gB1 + kt * 32, lB1);
    __syncthreads();
    bf16x8 af[4], bfv[4];
#pragma unroll
    for (int m = 0; m < 4; ++m)
      af[m] = *(const bf16x8*)(sA + (wr + m * 16 + fr) * 32 + fk);
#pragma unroll
    for (int n = 0; n < 4; ++n)
      bfv[n] = *(const bf16x8*)(sB + (wc + n * 16 + fr) * 32 + fk);
#pragma unroll
    for (int m = 0; m < 4; ++m)
#pragma unroll
      for (int n = 0; n < 4; ++n)
        acc[m][n] = __builtin_amdgcn_mfma_f32_16x16x32_bf16(af[m], bfv[n],
                                                            acc[m][n], 0, 0, 0);
  }
}

// ---- 256x256 deep-pipeline core (BK=64, 8 waves, K=512 fixed) ------------
#define C256_STAGE(kt, buf)                                    \
  {                                                            \
    const u16* a0 = Ag + (kt) * 64;                            \
    const u16* b0 = Bg + (kt) * 64;                            \
    u16* Lb = lds + (buf) * 32768;                             \
    gload16(a0 + offE0, Lb + d0);                              \
    gload16(a0 + offE1, Lb + d1);                              \
    gload16(a0 + 65536 + offE0, Lb + 8192 + d0);               \
    gload16(a0 + 65536 + offE1, Lb + 8192 + d1);               \
    gload16(b0 + offE0, Lb + 16384 + d0);                      \
    gload16(b0 + offE1, Lb + 16384 + d1);                      \
    gload16(b0 + 65536 + offE0, Lb + 24576 + d0);              \
    gload16(b0 + 65536 + offE1, Lb + 24576 + d1);              \
  }

DEVINL void core256(const u16* __restrict__ Ag, const u16* __restrict__ Bg,
                    u16* lds, f32x4 (&acc)[8][4], int tid) {
  const int lane = tid & 63, w = tid >> 6;
  const int wm = w >> 2, wn = w & 3;

  int offE0, offE1;
  {
    int q = tid;
    int r = (((q >> 6) >> 1) << 4) | ((q >> 2) & 15);
    int c = (((q >> 6) & 1) << 5) |
            (((q & 3) << 3) ^ (((q >> 5) & 1) << 4) ^ (((q >> 4) & 1) << 3));
    offE0 = r * DD + c;
    q = 512 + tid;
    r = (((q >> 6) >> 1) << 4) | ((q >> 2) & 15);
    c = (((q >> 6) & 1) << 5) |
        (((q & 3) << 3) ^ (((q >> 5) & 1) << 4) ^ (((q >> 4) & 1) << 3));
    offE1 = r * DD + c;
  }
  const int d0 = w * 512, d1 = 4096 + w * 512;  // u16 units in a half region

  int x = (lane & 15) * 64 + ((lane >> 4) & 3) * 16;  // bytes
  int fxu = (x ^ (((x >> 9) & 1) << 5) ^ (((x >> 8) & 1) << 4)) >> 1;

#pragma unroll
  for (int m = 0; m < 8; ++m)
#pragma unroll
    for (int n = 0; n < 4; ++n) {
      acc[m][n][0] = 0.f; acc[m][n][1] = 0.f;
      acc[m][n][2] = 0.f; acc[m][n][3] = 0.f;
    }

  C256_STAGE(0, 0);
  C256_STAGE(1, 1);
  asm volatile("s_waitcnt vmcnt(8)" ::: "memory");  // K-tile 0 landed
  __syncthreads();

  for (int c = 0; c < 8; ++c) {
    const u16* L = lds + (c & 1) * 32768;
    const u16* pa = L + wm * 8192;
    const u16* pb = L + 16384 + (wn >> 1) * 8192 + (wn & 1) * 4096;
    bf16x8 af[4][2], bf[4][2];
    // phase 1: quadrant (m0-3, n0-1)
#pragma unroll
    for (int n = 0; n < 2; ++n)
#pragma unroll
      for (int ks = 0; ks < 2; ++ks)
        bf[n][ks] = *(const bf16x8*)(pb + (n * 2 + ks) * 512 + fxu);
#pragma unroll
    for (int m = 0; m < 4; ++m)
#pragma unroll
      for (int ks = 0; ks < 2; ++ks)
        af[m][ks] = *(const bf16x8*)(pa + (m * 2 + ks) * 512 + fxu);
    __builtin_amdgcn_s_setprio(1);
#pragma unroll
    for (int m = 0; m < 4; ++m)
#pragma unroll
      for (int n = 0; n < 2; ++n)
#pragma unroll
        for (int ks = 0; ks < 2; ++ks)
          acc[m][n] = __builtin_amdgcn_mfma_f32_16x16x32_bf16(
              af[m][ks], bf[n][ks], acc[m][n], 0, 0, 0);
    __builtin_amdgcn_s_setprio(0);
    // phase 2: (m0-3, n2-3)
#pragma unroll
    for (int n = 2; n < 4; ++n)
#pragma unroll
      for (int ks = 0; ks < 2; ++ks)
        bf[n][ks] = *(const bf16x8*)(pb + (n * 2 + ks) * 512 + fxu);
    __builtin_amdgcn_s_setprio(1);
#pragma unroll
    for (int m = 0; m < 4; ++m)
#pragma unroll
      for (int n = 2; n < 4; ++n)
#pragma unroll
        for (int ks = 0; ks < 2; ++ks)
          acc[m][n] = __builtin_amdgcn_mfma_f32_16x16x32_bf16(
              af[m][ks], bf[n][ks], acc[m][n], 0, 0, 0);
    __builtin_amdgcn_s_setprio(0);
    // phase 3: (m4-7, n0-1)
#pragma unroll
    for (int m = 0; m < 4; ++m)
#pragma unroll
      for (int ks = 0; ks < 2; ++ks)
        af[m][ks] = *(const bf16x8*)(pa + ((m + 4) * 2 + ks) * 512 + fxu);
    __builtin_amdgcn_s_setprio(1);
#pragma unroll
    for (int m = 0; m < 4; ++m)
#pragma unroll
      for (int n = 0; n < 2; ++n)
#pragma unroll
        for (int ks = 0; ks < 2; ++ks)
          acc[m + 4][n] = __builtin_amdgcn_mfma_f32_16x16x32_bf16(
              af[m][ks], bf[n][ks], acc[m + 4][n], 0, 0, 0);
    // phase 4: (m4-7, n2-3)
#pragma unroll
    for (int m = 0; m < 4; ++m)
#pragma unroll
      for (int n = 2; n < 4; ++n)
#pragma unroll
        for (int ks = 0; ks < 2; ++ks)
          acc[m + 4][n] = __builtin_amdgcn_mfma_f32_16x16x32_bf16(
              af[m][ks], bf[n][ks], acc[m + 4][n], 0, 0, 0);
    __builtin_amdgcn_s_setprio(0);

    __syncthreads();  // all waves done READING buffer (c&1)
    if (c < 6) {
      C256_STAGE(c + 2, c & 1);  // overwrite just-read buffer (post-barrier)
      asm volatile("s_waitcnt vmcnt(8)" ::: "memory");  // K-tile c+1 landed
    } else if (c == 6) {
      asm volatile("s_waitcnt vmcnt(0)" ::: "memory");  // K-tile 7 landed
    }
    __syncthreads();
  }
}

// ---- merged prep: gather + 2x W transpose + Ey cast (one launch) ---------
__global__ __launch_bounds__(256) void prep_all(const int* __restrict__ Ms,
                                                const float* __restrict__ Ev,
                                                const float* __restrict__ WA,
                                                const float* __restrict__ WO,
                                                const float* __restrict__ Ey,
                                                u16* __restrict__ Xb,
                                                u16* __restrict__ WAt,
                                                u16* __restrict__ WOt,
                                                u16* __restrict__ Eyb) {
  __shared__ u16 t[64][65];
  int bx = blockIdx.x, tid = threadIdx.x;
  if (bx < 8192) {  // gather: 2 rows per block
    int row = bx * 2 + (tid >> 7);
    int t4 = tid & 127;
    int tok = Ms[row];
    float4 v = *(const float4*)(Ev + (size_t)tok * DD + t4 * 4);
    *(ushort4*)(Xb + (size_t)row * DD + t4 * 4) =
        make_ushort4(f2bf(v.x), f2bf(v.y), f2bf(v.z), f2bf(v.w));
  } else if (bx < 8320) {  // W transpose, 64 blocks each
    int k = bx - 8192;
    const float* W = (k < 64) ? WA : WO;
    u16* Wt = (k < 64) ? WAt : WOt;
    k &= 63;
    int dt = k >> 3, et = k & 7;
#pragma unroll
    for (int p = 0; p < 16; ++p) {
      int e = tid + 256 * p; int r = e >> 6, c = e & 63;
      t[r][c] = f2bf(W[(size_t)(dt * 64 + r) * DD + et * 64 + c]);
    }
    __syncthreads();
#pragma unroll
    for (int p = 0; p < 16; ++p) {
      int e = tid + 256 * p; int r = e >> 6, c = e & 63;
      Wt[(size_t)(et * 64 + r) * DD + dt * 64 + c] = t[c][r];
    }
  } else {  // prep_ey: 8064 blocks
    size_t i4 = (size_t)(bx - 8320) * 256 + tid;
    size_t row = i4 >> 7;
    ushort4 h;
    if (row < YY) {
      float4 v = *(const float4*)(Ey + i4 * 4);
      h = make_ushort4(f2bf(v.x), f2bf(v.y), f2bf(v.z), f2bf(v.w));
    } else {
      h = make_ushort4(0, 0, 0, 0);
    }
    *(ushort4*)(Eyb + i4 * 4) = h;
  }
}

// ---- k2w: merged k2 (XW_A) + k_wot ((X W_O)^T) — both read Xb ------------
__global__ __launch_bounds__(256) void k2w(const u16* __restrict__ Xb,
                                           const u16* __restrict__ WAt,
                                           const u16* __restrict__ WOt,
                                           u16* __restrict__ XWb,
                                           u16* __restrict__ XWoT) {
  __shared__ u16 sA[4096], sB[4096];
  f32x4 acc[4][4]; zero_acc(acc);
  int tid = threadIdx.x, bx = blockIdx.x;
  int lane = tid & 63, w = tid >> 6;
  int wr = (w >> 1) * 64, wc = (w & 1) * 64;
  int cr = (lane >> 4) * 4, cc = lane & 15;
  if (bx < 512) {  // k2: XWb[i][e] = X[i]. WAt[e]
    size_t row0 = (size_t)(bx >> 2) * 128, col0 = (size_t)(bx & 3) * 128;
    gemm_bt_core(Xb + row0 * DD, DD, WAt + col0 * DD, DD, DD / 32, sA, sB,
                 acc, tid);
#pragma unroll
    for (int m = 0; m < 4; ++m)
#pragma unroll
      for (int n = 0; n < 4; ++n)
#pragma unroll
        for (int r = 0; r < 4; ++r) {
          size_t gi = row0 + wr + m * 16 + cr + r;
          size_t gj = col0 + wc + n * 16 + cc;
          XWb[gi * DD + gj] = f2bf(acc[m][n][r]);
        }
  } else {  // k_wot: XWoT[b][e][i] = WOt[e] . X[b*NN+i]
    int j = bx - 512;
    int et = j & 3, it = (j >> 2) & 31, b = j >> 7;
    const u16* Ap = WOt + (size_t)et * 128 * DD;
    const u16* Bp = Xb + ((size_t)b * NN + it * 128) * DD;
    gemm_bt_core(Ap, DD, Bp, DD, DD / 32, sA, sB, acc, tid);
#pragma unroll
    for (int m = 0; m < 4; ++m)
#pragma unroll
      for (int n = 0; n < 4; ++n)
#pragma unroll
        for (int r = 0; r < 4; ++r) {
          size_t e = (size_t)et * 128 + wr + m * 16 + cr + r;
          size_t i = (size_t)it * 128 + wc + n * 16 + cc;
          XWoT[((size_t)b * DD + e) * NN + i] = f2bf(acc[m][n][r]);
        }
  }
}

// k3: triangular m97 grid; epilogue computes E=exp(S) (fixed shift m=0),
// writes bf16 E only. t in [0,528) -> (ib, jb<=ib).
__global__ __launch_bounds__(256) void k3_scores(const u16* __restrict__ XWb,
                                                 const u16* __restrict__ Xb,
                                                 u16* __restrict__ Ebf) {
  int t = blockIdx.x, b = blockIdx.z;
  int ib = (int)((sqrtf(8.f * (float)t + 1.f) - 1.f) * 0.5f);
  while ((ib + 1) * (ib + 2) / 2 <= t) ++ib;
  while (ib * (ib + 1) / 2 > t) --ib;
  int jb = t - ib * (ib + 1) / 2;
  __shared__ u16 sA[4096], sB[4096];
  f32x4 acc[4][4]; zero_acc(acc);
  int tid = threadIdx.x;
  const u16* Ap = XWb + ((size_t)b * NN + ib * 128) * DD;
  const u16* Bp = Xb  + ((size_t)b * NN + jb * 128) * DD;
  gemm_bt_core(Ap, DD, Bp, DD, DD / 32, sA, sB, acc, tid);
  int lane = tid & 63, w = tid >> 6;
  int wr = (w >> 1) * 64, wc = (w & 1) * 64;
  int cr = (lane >> 4) * 4, cc = lane & 15;
  u16* Eb = Ebf + (size_t)b * NN * NN;
#pragma unroll
  for (int m = 0; m < 4; ++m)
#pragma unroll
    for (int n = 0; n < 4; ++n)
#pragma unroll
      for (int r = 0; r < 4; ++r) {
        int i = ib * 128 + wr + m * 16 + cr + r;
        int j = jb * 128 + wc + n * 16 + cc;
        float e = (j > i) ? 0.f : __expf(acc[m][n][r] - (float)(i - j));
        Eb[(size_t)i * NN + j] = f2bf(e);
      }
}

// k5: rawQc = E @ (X W_O)  (no normalization — inv applied in k6b)
__global__ __launch_bounds__(256) void k5_ax(const u16* __restrict__ Ebf,
                                             const u16* __restrict__ XWoT,
                                             u16* __restrict__ Qcb) {
  int u = blockIdx.x;
  int half = u >> 8, v = u & 255;
  int ib = v & 31; if (half) ib = 31 - ib;
  int db = (v >> 5) & 3;
  int b = (half << 1) | (v >> 7);
  __shared__ u16 sA[4096], sB[4096];
  f32x4 acc[4][4]; zero_acc(acc);
  int tid = threadIdx.x;
  const u16* Ap = Ebf + ((size_t)b * NN + ib * 128) * NN;
  const u16* Bp = XWoT + ((size_t)b * DD + db * 128) * NN;
  gemm_bt_core(Ap, NN, Bp, NN, (ib + 1) * 4, sA, sB, acc, tid);
  int lane = tid & 63, w = tid >> 6;
  int wr = (w >> 1) * 64, wc = (w & 1) * 64;
  int cr = (lane >> 4) * 4, cc = lane & 15;
#pragma unroll
  for (int m = 0; m < 4; ++m)
#pragma unroll
    for (int n = 0; n < 4; ++n)
#pragma unroll
      for (int r = 0; r < 4; ++r) {
        int i = ib * 128 + wr + m * 16 + cr + r;
        int d = db * 128 + wc + n * 16 + cc;
        Qcb[((size_t)b * NN + i) * DD + d] = f2bf(acc[m][n][r]);
      }
}

// k4: row sums of E -> invb; write normalized f32 A (+ zero upper). Runs
// AFTER k5 so its 268MB write doesn't evict Ebf from L3 before k5.
__global__ __launch_bounds__(256) void k4_softmax(const u16* __restrict__ Ebf,
                                                  float* __restrict__ Aout,
                                                  float* __restrict__ invb) {
  __shared__ u16 srow[NN];  // 8KB
  __shared__ float red[4];
  size_t row = blockIdx.x;
  int i = (int)(row & (NN - 1));
  const u16* E = Ebf + row * (size_t)NN;
  float* S = Aout + row * (size_t)NN;
  int len = i + 1, tid = threadIdx.x;
  int padend = (len + 127) & ~127;  // k3 wrote exactly j < padend
  int nc = padend >> 3;             // 16B chunks
  for (int v = tid; v < nc; v += 256)
    *(uint4*)(srow + v * 8) = *(const uint4*)(E + v * 8);
  __syncthreads();
  float l = 0.f;
  for (int v = tid; v < nc; v += 256) {
    uint4 x = *(const uint4*)(srow + v * 8);
    l += bf2f((u16)(x.x & 0xffff)) + bf2f((u16)(x.x >> 16));
    l += bf2f((u16)(x.y & 0xffff)) + bf2f((u16)(x.y >> 16));
    l += bf2f((u16)(x.z & 0xffff)) + bf2f((u16)(x.z >> 16));
    l += bf2f((u16)(x.w & 0xffff)) + bf2f((u16)(x.w >> 16));
  }
#pragma unroll
  for (int o = 32; o; o >>= 1) l += __shfl_xor(l, o);
  if ((tid & 63) == 0) red[tid >> 6] = l;
  __syncthreads();
  float inv = 1.f / (red[0] + red[1] + red[2] + red[3]);
  if (tid == 0) invb[row] = inv;
  for (int v = tid; v < NN / 4; v += 256) {
    int k = v * 4;
    float4 a = make_float4(0.f, 0.f, 0.f, 0.f);
    if (k < padend) {
      ushort4 e = *(const ushort4*)(srow + k);
      a = make_float4(bf2f(e.x) * inv, bf2f(e.y) * inv,
                      bf2f(e.z) * inv, bf2f(e.w) * inv);
    }
    *(float4*)(S + k) = a;
  }
}

// k6b: H = LN(inv[i]*rawQc + X)
__global__ __launch_bounds__(128) void k6b_ln(const u16* __restrict__ Qcb,
                                              const u16* __restrict__ Xb,
                                              const float* __restrict__ invb,
                                              const float* __restrict__ gamma,
                                              const float* __restrict__ beta,
                                              u16* __restrict__ Hb) {
  int row = blockIdx.x, tid = threadIdx.x;
  float inv = invb[row];
  ushort4 qu = *(const ushort4*)(Qcb + (size_t)row * DD + tid * 4);
  ushort4 xu = *(const ushort4*)(Xb + (size_t)row * DD + tid * 4);
  float v0 = bf2f(qu.x) * inv + bf2f(xu.x), v1 = bf2f(qu.y) * inv + bf2f(xu.y);
  float v2 = bf2f(qu.z) * inv + bf2f(xu.z), v3 = bf2f(qu.w) * inv + bf2f(xu.w);
  float s = v0 + v1 + v2 + v3;
  float s2 = v0 * v0 + v1 * v1 + v2 * v2 + v3 * v3;
#pragma unroll
  for (int o = 32; o; o >>= 1) { s += __shfl_xor(s, o); s2 += __shfl_xor(s2, o); }
  __shared__ float r1[2], r2[2];
  int lane = tid & 63, w = tid >> 6;
  if (lane == 0) { r1[w] = s; r2[w] = s2; }
  __syncthreads();
  s = r1[0] + r1[1]; s2 = r2[0] + r2[1];
  float mu = s * (1.f / 512.f);
  float var = s2 * (1.f / 512.f) - mu * mu;
  float rs = 1.f / sqrtf(var + 1e-5f);
  float4 g  = *(const float4*)(gamma + tid * 4);
  float4 be = *(const float4*)(beta + tid * 4);
  ushort4 h = make_ushort4(f2bf((v0 - mu) * rs * g.x + be.x),
                           f2bf((v1 - mu) * rs * g.y + be.y),
                           f2bf((v2 - mu) * rs * g.z + be.z),
                           f2bf((v3 - mu) * rs * g.w + be.w));
  *(ushort4*)(Hb + (size_t)row * DD + tid * 4) = h;
}

// ---- k7: y = H E_y^T on the 256^2 core, direct stores (lanes 0-15 span
// consecutive y-columns -> 64B/quarter-wave coalescing) --------------------
__global__ __launch_bounds__(512, 2) void k7_logits(const u16* __restrict__ Hb,
                                                    const u16* __restrict__ Eyb,
                                                    float* __restrict__ Yout) {
  __shared__ u16 lds[65536];  // 128 KB
  const int tid = threadIdx.x;
  const int lane = tid & 63, w = tid >> 6;
  const int wm = w >> 2, wn = w & 3;

  // bijective XCD swizzle (4032 % 8 == 0); consecutive swz share B panel
  int id = blockIdx.x;
  int swz = (id & 7) * (4032 / 8) + (id >> 3);
  size_t row0 = (size_t)(swz & 63) * 256;
  size_t col0 = (size_t)(swz >> 6) * 256;

  f32x4 acc[8][4];
  core256(Hb + row0 * DD, Eyb + col0 * DD, lds, acc, tid);

  // epilogue: direct plain stores
  const int cr = (lane >> 4) * 4, cc = lane & 15;
#pragma unroll
  for (int m = 0; m < 8; ++m)
#pragma unroll
    for (int n = 0; n < 4; ++n) {
      size_t gj = col0 + wn * 64 + n * 16 + cc;
      if (gj < YY) {
        size_t gi = row0 + wm * 128 + m * 16 + cr;
#pragma unroll
        for (int rr = 0; rr < 4; ++rr)
          Yout[(gi + rr) * (size_t)YY + gj] = acc[m][n][rr];
      }
    }
}

extern "C" void kernel_launch(void* const* d_in, const int* in_sizes, int n_in,
                              void* d_out, int out_size, void* d_ws, size_t ws_size,
                              hipStream_t stream) {
  (void)in_sizes; (void)n_in; (void)out_size; (void)ws_size;
  const int*   Ms    = (const int*)d_in[0];
  const float* Ev    = (const float*)d_in[1];
  const float* Ey    = (const float*)d_in[2];
  const float* WA    = (const float*)d_in[3];
  const float* WO    = (const float*)d_in[4];
  const float* gamma = (const float*)d_in[5];
  const float* beta  = (const float*)d_in[6];

  float* Yout = (float*)d_out;
  float* Aout = Yout + (size_t)BB * NN * YY;  // A region of d_out

  // workspace carve (~236 MB)
  char* w = (char*)d_ws;
  u16* Xb   = (u16*)w; w += (size_t)ROWS * DD * 2;     // 16.8 MB
  u16* XWoT = (u16*)w; w += (size_t)BB * DD * NN * 2;  // 16.8 MB ((X W_O)^T)
  u16* XWb  = (u16*)w; w += (size_t)ROWS * DD * 2;     // 16.8 MB
  u16* Hb   = (u16*)w; w += (size_t)ROWS * DD * 2;     // 16.8 MB
  u16* WAt  = (u16*)w; w += (size_t)DD * DD * 2;       // 0.5 MB
  u16* WOt  = (u16*)w; w += (size_t)DD * DD * 2;       // 0.5 MB
  u16* Eyb  = (u16*)w; w += (size_t)YPAD * DD * 2;     // 16.5 MB (padded)
  u16* Ebf  = (u16*)w; w += (size_t)ROWS * NN * 2;     // 134.2 MB (exp(S) bf16)
  float* invb = (float*)w; w += (size_t)ROWS * 4;      // 64 KB (row inv sums)
  u16* Qcb = XWb;  // aliases XWb — dead after k3; k5 writes it post-k3

  prep_all<<<16384, 256, 0, stream>>>(Ms, Ev, WA, WO, Ey, Xb, WAt, WOt, Eyb);
  k2w<<<1024, 256, 0, stream>>>(Xb, WAt, WOt, XWb, XWoT);
  k3_scores<<<dim3(528, 1, BB), 256, 0, stream>>>(XWb, Xb, Ebf);
  k5_ax<<<512, 256, 0, stream>>>(Ebf, XWoT, Qcb);
  k4_softmax<<<ROWS, 256, 0, stream>>>(Ebf, Aout, invb);
  k6b_ln<<<ROWS, 128, 0, stream>>>(Qcb, Xb, invb, gamma, beta, Hb);
  k7_logits<<<dim3(64 * 63), 512, 0, stream>>>(Hb, Eyb, Yout);
}